// Round 1
// baseline (221.564 us; speedup 1.0000x reference)
//
#include <hip/hip_runtime.h>

#define VOCAB 50257
#define M 10
#define NPERM 3628800   // 10!
#define PERM_BLOCKS 14175  // 3628800 / 256

// ws layout (as float*):
//   [0..9]    rowmax
//   [10..19]  rowsum (sum of exp(x - rowmax))
//   [20..119] S[i][k] = prob[i, target[k]]  (row-major, S[i*10+k])
// byte offset 512: unsigned long long bestkey

// ---------------- kernel 1: per-row max and sum(exp) ----------------
__global__ __launch_bounds__(256) void rowstats_kernel(
    const float* __restrict__ logits, float* __restrict__ ws) {
    const int row = blockIdx.x;
    const float* __restrict__ x = logits + (size_t)row * VOCAB;
    const int tid = threadIdx.x;
    __shared__ float wred[4];

    // pass 1: max
    float m = -3.4e38f;
    for (int j = tid; j < VOCAB; j += 256) m = fmaxf(m, x[j]);
    #pragma unroll
    for (int off = 32; off; off >>= 1) m = fmaxf(m, __shfl_down(m, off, 64));
    if ((tid & 63) == 0) wred[tid >> 6] = m;
    __syncthreads();
    const float rm = fmaxf(fmaxf(wred[0], wred[1]), fmaxf(wred[2], wred[3]));
    __syncthreads();

    // pass 2: sum of exp(x - max)  (second read is L2-hot)
    float s = 0.f;
    for (int j = tid; j < VOCAB; j += 256) s += expf(x[j] - rm);
    #pragma unroll
    for (int off = 32; off; off >>= 1) s += __shfl_down(s, off, 64);
    if ((tid & 63) == 0) wred[tid >> 6] = s;
    __syncthreads();
    if (tid == 0) {
        ws[row]      = rm;
        ws[10 + row] = wred[0] + wred[1] + wred[2] + wred[3];
    }
}

// ---------------- kernel 2: S matrix + bestkey init ----------------
__global__ __launch_bounds__(128) void prep_kernel(
    const float* __restrict__ logits, const int* __restrict__ target,
    float* __restrict__ ws, unsigned long long* __restrict__ best) {
    const int tid = threadIdx.x;
    if (tid == 0) *best = 0ull;
    if (tid < 100) {
        const int i = tid / 10;       // row
        const int k = tid % 10;       // which target slot
        const int t = target[k];
        const float v = expf(logits[(size_t)i * VOCAB + t] - ws[i]) / ws[10 + i];
        ws[20 + tid] = v;             // S[i][k]
    }
}

// ---------------- kernel 3: scan all 10! permutations ----------------
__global__ __launch_bounds__(256) void perm_kernel(
    const float* __restrict__ ws, unsigned long long* __restrict__ best) {
    __shared__ float S[100];
    const int tid = threadIdx.x;
    if (tid < 100) S[tid] = ws[20 + tid];
    __syncthreads();

    const unsigned int idx = blockIdx.x * 256u + tid;  // perm index, < 3628800
    unsigned int p = idx;
    unsigned long long avail = 0x9876543210ull;        // nibble list 0..9
    float score = 0.f;
    const unsigned int fact[9] = {362880u, 40320u, 5040u, 720u, 120u, 24u, 6u, 2u, 1u};
    #pragma unroll
    for (int pos = 0; pos < 9; ++pos) {
        const unsigned int f = fact[pos];       // compile-time constant per iter
        const unsigned int d = p / f;           // magic-mul division
        p -= d * f;
        const unsigned int sh = d * 4u;
        const unsigned int sym = (unsigned int)(avail >> sh) & 0xFu;
        const unsigned long long low  = avail & ((1ull << sh) - 1ull);
        const unsigned long long high = (avail >> (sh + 4u)) << sh;
        avail = low | high;
        score += S[pos * 10 + sym];
    }
    score += S[90 + (int)(avail & 0xFull)];     // last remaining symbol

    // pack: larger score wins; tie -> smaller index (first occurrence, like argmax)
    unsigned long long key =
        ((unsigned long long)__float_as_uint(score) << 32) |
        (unsigned long long)(0xFFFFFFFFu - idx);

    #pragma unroll
    for (int off = 32; off; off >>= 1) {
        const unsigned long long o = __shfl_down(key, off, 64);
        if (o > key) key = o;
    }
    __shared__ unsigned long long wk[4];
    if ((tid & 63) == 0) wk[tid >> 6] = key;
    __syncthreads();
    if (tid == 0) {
        unsigned long long k = wk[0];
        #pragma unroll
        for (int w = 1; w < 4; ++w) if (wk[w] > k) k = wk[w];
        atomicMax(best, k);
    }
}

// ---------------- kernel 4: finalize outputs ----------------
__global__ __launch_bounds__(64) void final_kernel(
    const float* __restrict__ logits, const int* __restrict__ target,
    const float* __restrict__ ws, const unsigned long long* __restrict__ best,
    float* __restrict__ out) {
    __shared__ int perm[10];
    if (threadIdx.x == 0) {
        const unsigned int idx = 0xFFFFFFFFu - (unsigned int)(*best & 0xFFFFFFFFull);
        unsigned int p = idx;
        unsigned long long avail = 0x9876543210ull;
        const unsigned int fact[9] = {362880u, 40320u, 5040u, 720u, 120u, 24u, 6u, 2u, 1u};
        #pragma unroll
        for (int pos = 0; pos < 9; ++pos) {
            const unsigned int f = fact[pos];
            const unsigned int d = p / f;
            p -= d * f;
            const unsigned int sh = d * 4u;
            perm[pos] = (int)((avail >> sh) & 0xFull);
            const unsigned long long low  = avail & ((1ull << sh) - 1ull);
            const unsigned long long high = (avail >> (sh + 4u)) << sh;
            avail = low | high;
        }
        perm[9] = (int)(avail & 0xFull);
    }
    __syncthreads();
    const int i = threadIdx.x;
    if (i < 10) {
        const int tb = target[perm[i]];
        const float logp = logits[(size_t)i * VOCAB + tb] - ws[i] - logf(ws[10 + i]);
        out[i]      = -logp;            // loss
        out[10 + i] = (float)tb;        // target_best (exact in f32)
    }
}

extern "C" void kernel_launch(void* const* d_in, const int* in_sizes, int n_in,
                              void* d_out, int out_size, void* d_ws, size_t ws_size,
                              hipStream_t stream) {
    const float* logits = (const float*)d_in[0];
    const int*   target = (const int*)d_in[1];
    // d_in[2] (perms) is intentionally unused: it is itertools.permutations(range(10))
    // in lexicographic order, which we decode on-device (avoids a 145 MB read).
    float* ws = (float*)d_ws;
    unsigned long long* best = (unsigned long long*)((char*)d_ws + 512);
    float* out = (float*)d_out;

    rowstats_kernel<<<10, 256, 0, stream>>>(logits, ws);
    prep_kernel<<<1, 128, 0, stream>>>(logits, target, ws, best);
    perm_kernel<<<PERM_BLOCKS, 256, 0, stream>>>(ws, best);
    final_kernel<<<1, 64, 0, stream>>>(logits, target, ws, best, out);
}

// Round 2
// 18.202 us; speedup vs baseline: 12.1724x; 12.1724x over previous
//
#include <hip/hip_runtime.h>

#define VOCAB 50257
#define M 10
#define NPERM 3628800          // 10!
#define CHUNKS 32              // chunks per row for rowstats
#define CH 1571                // ceil(50257/32)
#define NTHREADS_PERM 151200   // 3628800 / 24 perms per thread
#define PERM_BLOCKS 591        // ceil(151200/256)

// ws layout (float offsets):
#define WS_PMAX 0     // 320: per-chunk max
#define WS_PSUM 320   // 320: per-chunk sum(exp(x - chunkmax))
#define WS_RMAX 640   // 10 : row max
#define WS_RSUM 656   // 10 : row sum(exp(x - rowmax))
#define WS_S    672   // 100: S[i][k] = prob[i, target[k]]
// byte offset 4096: unsigned long long keys[PERM_BLOCKS]

// -------- kernel 1: per-chunk max + sumexp (single HBM pass over logits) ----
__global__ __launch_bounds__(256) void chunkstats_kernel(
    const float* __restrict__ logits, float* __restrict__ ws) {
    const int r = blockIdx.x >> 5;        // row
    const int c = blockIdx.x & 31;        // chunk
    const int s = c * CH;
    const int e = (s + CH < VOCAB) ? s + CH : VOCAB;
    const float* __restrict__ x = logits + (size_t)r * VOCAB;
    const int tid = threadIdx.x;
    __shared__ float wred[4];

    float m = -3.4e38f;
    for (int j = s + tid; j < e; j += 256) m = fmaxf(m, x[j]);
    #pragma unroll
    for (int off = 32; off; off >>= 1) m = fmaxf(m, __shfl_down(m, off, 64));
    if ((tid & 63) == 0) wred[tid >> 6] = m;
    __syncthreads();
    const float cm = fmaxf(fmaxf(wred[0], wred[1]), fmaxf(wred[2], wred[3]));
    __syncthreads();

    // second pass is L1-hot (chunk = 6.3 KB < 32 KB L1)
    float sum = 0.f;
    for (int j = s + tid; j < e; j += 256) sum += expf(x[j] - cm);
    #pragma unroll
    for (int off = 32; off; off >>= 1) sum += __shfl_down(sum, off, 64);
    if ((tid & 63) == 0) wred[tid >> 6] = sum;
    __syncthreads();
    if (tid == 0) {
        ws[WS_PMAX + blockIdx.x] = cm;
        ws[WS_PSUM + blockIdx.x] = wred[0] + wred[1] + wred[2] + wred[3];
    }
}

// -------- kernel 2: combine chunk stats -> row stats, build S --------------
__global__ __launch_bounds__(320) void combine_kernel(
    const float* __restrict__ logits, const int* __restrict__ target,
    float* __restrict__ ws) {
    const int tid = threadIdx.x;
    const int r = tid >> 5;               // row 0..9
    const float lm = ws[WS_PMAX + tid];
    float m = lm;
    #pragma unroll
    for (int off = 16; off; off >>= 1) m = fmaxf(m, __shfl_xor(m, off, 32));
    float contrib = ws[WS_PSUM + tid] * expf(lm - m);
    #pragma unroll
    for (int off = 16; off; off >>= 1) contrib += __shfl_xor(contrib, off, 32);
    if ((tid & 31) == 0) {
        ws[WS_RMAX + r] = m;
        ws[WS_RSUM + r] = contrib;
    }
    __syncthreads();
    if (tid < 100) {
        const int i = tid / 10;           // row
        const int k = tid % 10;           // target slot
        const int t = target[k];
        ws[WS_S + tid] =
            expf(logits[(size_t)i * VOCAB + t] - ws[WS_RMAX + i]) / ws[WS_RSUM + i];
    }
}

// -------- kernel 3: scan all 10! perms, 24 per thread ----------------------
__global__ __launch_bounds__(256) void perm_kernel(
    const float* __restrict__ ws, unsigned long long* __restrict__ keys) {
    __shared__ float S[100];
    const int tid = threadIdx.x;
    if (tid < 100) S[tid] = ws[WS_S + tid];
    __syncthreads();

    const unsigned int t = blockIdx.x * 256u + tid;
    unsigned long long key = 0ull;
    if (t < NTHREADS_PERM) {
        const unsigned int base = t * 24u;     // first perm index of this thread
        unsigned int p = base;
        unsigned long long avail = 0x9876543210ull;
        float prefix = 0.f;
        const unsigned int fact6[6] = {362880u, 40320u, 5040u, 720u, 120u, 24u};
        #pragma unroll
        for (int pos = 0; pos < 6; ++pos) {
            const unsigned int f = fact6[pos];
            const unsigned int d = p / f;      // magic-mul (f is compile-time)
            p -= d * f;
            const unsigned int sh = d * 4u;
            const unsigned int sym = (unsigned int)(avail >> sh) & 0xFu;
            avail = (avail & ((1ull << sh) - 1ull)) | ((avail >> (sh + 4u)) << sh);
            prefix += S[pos * 10 + sym];       // left-fold order == reference
        }
        // remaining 4 symbols, ascending
        const int q0 = (int)(avail & 0xF),        q1 = (int)((avail >> 4) & 0xF);
        const int q2 = (int)((avail >> 8) & 0xF), q3 = (int)((avail >> 12) & 0xF);
        const float s6[4] = {S[60+q0], S[60+q1], S[60+q2], S[60+q3]};
        const float s7[4] = {S[70+q0], S[70+q1], S[70+q2], S[70+q3]};
        const float s8[4] = {S[80+q0], S[80+q1], S[80+q2], S[80+q3]};
        const float s9[4] = {S[90+q0], S[90+q1], S[90+q2], S[90+q3]};
        // lexicographic permutations of (0,1,2,3)
        constexpr unsigned char P[24][4] = {
            {0,1,2,3},{0,1,3,2},{0,2,1,3},{0,2,3,1},{0,3,1,2},{0,3,2,1},
            {1,0,2,3},{1,0,3,2},{1,2,0,3},{1,2,3,0},{1,3,0,2},{1,3,2,0},
            {2,0,1,3},{2,0,3,1},{2,1,0,3},{2,1,3,0},{2,3,0,1},{2,3,1,0},
            {3,0,1,2},{3,0,2,1},{3,1,0,2},{3,1,2,0},{3,2,0,1},{3,2,1,0}};
        float best = -1.f; unsigned int bl = 0;
        #pragma unroll
        for (int l = 0; l < 24; ++l) {
            const float sc =
                (((prefix + s6[P[l][0]]) + s7[P[l][1]]) + s8[P[l][2]]) + s9[P[l][3]];
            if (sc > best) { best = sc; bl = (unsigned int)l; }  // first-max tie-break
        }
        const unsigned int gidx = base + bl;
        key = ((unsigned long long)__float_as_uint(best) << 32) |
              (unsigned long long)(0xFFFFFFFFu - gidx);
    }
    // block reduce, plain store (no global atomic)
    #pragma unroll
    for (int off = 32; off; off >>= 1) {
        const unsigned long long o = __shfl_down(key, off, 64);
        if (o > key) key = o;
    }
    __shared__ unsigned long long wk[4];
    if ((tid & 63) == 0) wk[tid >> 6] = key;
    __syncthreads();
    if (tid == 0) {
        unsigned long long k = wk[0];
        #pragma unroll
        for (int w = 1; w < 4; ++w) if (wk[w] > k) k = wk[w];
        keys[blockIdx.x] = k;
    }
}

// -------- kernel 4: reduce block keys, decode best perm, write outputs -----
__global__ __launch_bounds__(256) void final_kernel(
    const float* __restrict__ logits, const int* __restrict__ target,
    const float* __restrict__ ws, const unsigned long long* __restrict__ keys,
    float* __restrict__ out) {
    const int tid = threadIdx.x;
    unsigned long long k = 0ull;
    for (int i = tid; i < PERM_BLOCKS; i += 256) {
        const unsigned long long v = keys[i];
        if (v > k) k = v;
    }
    #pragma unroll
    for (int off = 32; off; off >>= 1) {
        const unsigned long long o = __shfl_down(k, off, 64);
        if (o > k) k = o;
    }
    __shared__ unsigned long long wk[4];
    __shared__ int perm[10];
    if ((tid & 63) == 0) wk[tid >> 6] = k;
    __syncthreads();
    if (tid == 0) {
        unsigned long long kk = wk[0];
        #pragma unroll
        for (int w = 1; w < 4; ++w) if (wk[w] > kk) kk = wk[w];
        unsigned int p = 0xFFFFFFFFu - (unsigned int)(kk & 0xFFFFFFFFull);
        unsigned long long avail = 0x9876543210ull;
        const unsigned int fact[9] = {362880u, 40320u, 5040u, 720u, 120u, 24u, 6u, 2u, 1u};
        #pragma unroll
        for (int pos = 0; pos < 9; ++pos) {
            const unsigned int f = fact[pos];
            const unsigned int d = p / f;
            p -= d * f;
            const unsigned int sh = d * 4u;
            perm[pos] = (int)((avail >> sh) & 0xFull);
            avail = (avail & ((1ull << sh) - 1ull)) | ((avail >> (sh + 4u)) << sh);
        }
        perm[9] = (int)(avail & 0xFull);
    }
    __syncthreads();
    if (tid < 10) {
        const int tb = target[perm[tid]];
        const float logp =
            logits[(size_t)tid * VOCAB + tb] - ws[WS_RMAX + tid] - logf(ws[WS_RSUM + tid]);
        out[tid]      = -logp;
        out[10 + tid] = (float)tb;
    }
}

extern "C" void kernel_launch(void* const* d_in, const int* in_sizes, int n_in,
                              void* d_out, int out_size, void* d_ws, size_t ws_size,
                              hipStream_t stream) {
    const float* logits = (const float*)d_in[0];
    const int*   target = (const int*)d_in[1];
    // d_in[2] (perms) unused: lexicographic permutations decoded on-device.
    float* ws = (float*)d_ws;
    unsigned long long* keys = (unsigned long long*)((char*)d_ws + 4096);
    float* out = (float*)d_out;

    chunkstats_kernel<<<10 * CHUNKS, 256, 0, stream>>>(logits, ws);
    combine_kernel<<<1, 320, 0, stream>>>(logits, target, ws);
    perm_kernel<<<PERM_BLOCKS, 256, 0, stream>>>(ws, keys);
    final_kernel<<<1, 256, 0, stream>>>(logits, target, ws, keys, out);
}